// Round 4
// baseline (11343.668 us; speedup 1.0000x reference)
//
#include <hip/hip_runtime.h>

// LSTM encoder-decoder B=512 F=1024 HIST=20 FUT=30 L=3 (fp32 in/out).
// Round 4: split-bf16 MFMA GEMM (round-3 128x128/BK=32 shape, the ~920 TF
// plateau) with two structural changes:
//  1. Encoder wavefront batching: cells (l, t=w-l) are independent within a
//     wavefront -> up to 3 cells per launch (22 slots instead of 60).
//     Split-h state is parity-doubled (by t&1) to avoid same-launch WAR races.
//  2. In-kernel fuse-on-last-arrival: GEMM N-tiles are gate-interleaved
//     (n' = gate*32 + f) so a 128x128 patch holds all 4 gates for 32 f's.
//     The 4 sibling blocks (x/h operand x k-half) write fp32 partials; the
//     last to arrive at a per-patch atomic counter performs the LSTM cell
//     update in-kernel (release/acquire via __threadfence + device atomics).
//     No separate cell_fuse launch; no spinning (no deadlock possible).

#define BDIM 512
#define FDIM 1024
#define HISTLEN 20
#define LAYERS 3
#define NG 4096
#define KD 1024

constexpr size_t BF  = (size_t)BDIM * FDIM;     // 524288
constexpr size_t MNc = (size_t)BDIM * NG;       // gate matrix elems

typedef __attribute__((ext_vector_type(8))) short short8;     // 8 bf16
typedef __attribute__((ext_vector_type(4))) float f32x4;      // MFMA acc
typedef __attribute__((ext_vector_type(4))) unsigned short ushort4v;

__device__ __forceinline__ float sigf(float x) { return 1.f / (1.f + __expf(-x)); }
__device__ __forceinline__ float tanh_fast(float x) {
    float e = __expf(-2.f * fabsf(x));
    float r = (1.f - e) / (1.f + e);
    return copysignf(r, x);
}
__device__ __host__ __forceinline__ ushort bfhi_u(float w) {
    union { float f; unsigned u; } v; v.f = w; return (ushort)(v.u >> 16);
}
__device__ __forceinline__ ushort bfhi(float w) { return (ushort)(__float_as_uint(w) >> 16); }
__device__ __forceinline__ float hif(float w) { return __uint_as_float(__float_as_uint(w) & 0xFFFF0000u); }
__device__ __forceinline__ ushort bflo(float w) { return bfhi(w - hif(w)); }

struct Slice { const ushort* Ahi; const ushort* Alo; const float* W; };
struct CellCtl {
    float* gp;          // 4 partial gate matrices [zz][512][4096]
    unsigned* cnt;      // 128 per-patch counters
    const float* bi; const float* bh;
    float* c;           // [512][1024] in-place
    ushort* Hhi; ushort* Hlo;   // split h output (parity buffer)
    float* y;           // out base or null
    int t; int fut;
};
struct Args { Slice sl[12]; CellCtl cell[3]; };

// ---------------- GEMM + fused cell epilogue ----------------
// blockIdx: x = f-patch (32), y = m-patch (4), z = cellpos*4 + zz,
//   zz = (operand<<1)|khalf.  Tile 128m x 128n', n' = gate*32 + f_local.
constexpr int LDT = 40;   // padded LDS row stride (bf16 elems)

__global__ __launch_bounds__(256, 2) void gemm_fused(Args a)
{
    __shared__ __attribute__((aligned(16))) ushort WhiL[128 * LDT];
    __shared__ __attribute__((aligned(16))) ushort WloL[128 * LDT];
    __shared__ __attribute__((aligned(16))) ushort AhiL[128 * LDT];
    __shared__ __attribute__((aligned(16))) ushort AloL[128 * LDT];
    __shared__ int sflag;

    const int cellpos = blockIdx.z >> 2;
    const int zz      = blockIdx.z & 3;
    const int kh      = zz & 1;
    const Slice   sl = a.sl[blockIdx.z];
    const CellCtl cc = a.cell[cellpos];

    const int tid = threadIdx.x;
    const int m0 = blockIdx.y * 128;
    const int f0 = blockIdx.x * 32;

    const int srow  = tid >> 1;
    const int shalf = tid & 1;
    const int s_lds = srow * LDT + shalf * 16;

    const int lane = tid & 63;
    const int wid  = tid >> 6;
    const int wm = (wid & 1) * 64;
    const int wn = (wid >> 1) * 64;
    const int frow = lane & 15;
    const int oct  = lane >> 4;

    int a_off[4], w_off[4];
    #pragma unroll
    for (int i = 0; i < 4; ++i) {
        a_off[i] = (wm + i * 16 + frow) * LDT + oct * 8;
        w_off[i] = (wn + i * 16 + frow) * LDT + oct * 8;
    }

    f32x4 acc[4][4] = {};

    // gate-interleaved W row: LDS row r <-> global W row (r>>5)*F + f0 + (r&31)
    const int wrow_g = ((srow >> 5) * FDIM) + f0 + (srow & 31);
    const float*  wg_base = sl.W   + (size_t)wrow_g * KD + shalf * 16;
    const ushort* ah_base = sl.Ahi + (size_t)(m0 + srow) * KD + shalf * 16;
    const ushort* al_base = sl.Alo + (size_t)(m0 + srow) * KD + shalf * 16;

    const int kbeg = kh * (KD / 2);
    const int kend = kbeg + KD / 2;

    for (int k0 = kbeg; k0 < kend; k0 += 32) {
        float4 w4[4];
        #pragma unroll
        for (int q = 0; q < 4; ++q) w4[q] = *(const float4*)(wg_base + k0 + q * 4);
        short8 ah0 = *(const short8*)(ah_base + k0);
        short8 ah1 = *(const short8*)(ah_base + k0 + 8);
        short8 al0 = *(const short8*)(al_base + k0);
        short8 al1 = *(const short8*)(al_base + k0 + 8);

        ushort whi[16], wlo[16];
        #pragma unroll
        for (int e = 0; e < 16; ++e) {
            float w = ((const float*)w4)[e];
            unsigned u = __float_as_uint(w);
            whi[e] = (ushort)(u >> 16);
            float r = w - __uint_as_float(u & 0xFFFF0000u);
            wlo[e] = (ushort)(__float_as_uint(r) >> 16);
        }

        __syncthreads();
        *(short8*)&WhiL[s_lds]     = *(short8*)&whi[0];
        *(short8*)&WhiL[s_lds + 8] = *(short8*)&whi[8];
        *(short8*)&WloL[s_lds]     = *(short8*)&wlo[0];
        *(short8*)&WloL[s_lds + 8] = *(short8*)&wlo[8];
        *(short8*)&AhiL[s_lds]     = ah0;
        *(short8*)&AhiL[s_lds + 8] = ah1;
        *(short8*)&AloL[s_lds]     = al0;
        *(short8*)&AloL[s_lds + 8] = al1;
        __syncthreads();

        short8 fa_hi[4], fa_lo[4];
        #pragma unroll
        for (int i = 0; i < 4; ++i) {
            fa_hi[i] = *(const short8*)&AhiL[a_off[i]];
            fa_lo[i] = *(const short8*)&AloL[a_off[i]];
        }
        #pragma unroll
        for (int j = 0; j < 4; ++j) {
            short8 fb_hi = *(const short8*)&WhiL[w_off[j]];
            short8 fb_lo = *(const short8*)&WloL[w_off[j]];
            #pragma unroll
            for (int i = 0; i < 4; ++i) {
                acc[i][j] = __builtin_amdgcn_mfma_f32_16x16x32_bf16(fa_hi[i], fb_hi, acc[i][j], 0, 0, 0);
                acc[i][j] = __builtin_amdgcn_mfma_f32_16x16x32_bf16(fa_lo[i], fb_hi, acc[i][j], 0, 0, 0);
                acc[i][j] = __builtin_amdgcn_mfma_f32_16x16x32_bf16(fa_hi[i], fb_lo, acc[i][j], 0, 0, 0);
            }
        }
    }

    // partial store: C/D layout row=(lane>>4)*4+reg, col=lane&15
    float* gout = cc.gp + (size_t)zz * MNc;
    #pragma unroll
    for (int i = 0; i < 4; ++i) {
        #pragma unroll
        for (int j = 0; j < 4; ++j) {
            int col = blockIdx.x * 128 + wn + j * 16 + frow;
            #pragma unroll
            for (int r = 0; r < 4; ++r) {
                int row = m0 + wm + i * 16 + oct * 4 + r;
                gout[(size_t)row * NG + col] = acc[i][j][r];
            }
        }
    }

    // ---- fuse-on-last-arrival ----
    __syncthreads();                       // per-wave vmcnt(0) drain: partials complete
    unsigned* cp = cc.cnt + blockIdx.y * 32 + blockIdx.x;
    if (tid == 0) {
        __threadfence();                   // release: partials visible device-wide
        unsigned old = atomicAdd(cp, 1u);  // device scope
        sflag = (old == 3);
        if (old == 3) *cp = 0;             // reset for next reuse (next launch)
    }
    __syncthreads();
    if (!sflag) return;
    __threadfence();                       // acquire: invalidate stale L1/L2 lines

    const float* gpc = cc.gp;
    const float* bi = cc.bi;
    const float* bh = cc.bh;
    #pragma unroll
    for (int p = 0; p < 4; ++p) {
        int idx = p * 256 + tid;           // 0..1023 -> (m 0..127, fq 0..28 step4)
        int m  = idx >> 3;
        int fq = (idx & 7) * 4;
        int row = m0 + m;
        int fglob = f0 + fq;
        size_t gbase = (size_t)row * NG + (size_t)blockIdx.x * 128;

        float gs[4][4];
        #pragma unroll
        for (int g = 0; g < 4; ++g) {
            float4 s  = *(const float4*)(bi + g * FDIM + fglob);
            float4 s2 = *(const float4*)(bh + g * FDIM + fglob);
            gs[g][0] = s.x + s2.x; gs[g][1] = s.y + s2.y;
            gs[g][2] = s.z + s2.z; gs[g][3] = s.w + s2.w;
            #pragma unroll
            for (int z2 = 0; z2 < 4; ++z2) {
                float4 v = *(const float4*)(gpc + (size_t)z2 * MNc + gbase + g * 32 + fq);
                gs[g][0] += v.x; gs[g][1] += v.y; gs[g][2] += v.z; gs[g][3] += v.w;
            }
        }
        size_t cidx = (size_t)row * FDIM + fglob;
        float4 cold = *(const float4*)(cc.c + cidx);
        float co[4] = {cold.x, cold.y, cold.z, cold.w};
        float cn[4], hn[4];
        ushort hh[4], hl[4];
        #pragma unroll
        for (int e = 0; e < 4; ++e) {
            float cv = sigf(gs[1][e]) * co[e] + sigf(gs[0][e]) * tanh_fast(gs[2][e]);
            float hv = sigf(gs[3][e]) * tanh_fast(cv);
            cn[e] = cv; hn[e] = hv;
            hh[e] = bfhi(hv); hl[e] = bflo(hv);
        }
        *(float4*)(cc.c + cidx) = make_float4(cn[0], cn[1], cn[2], cn[3]);
        ushort4v h4 = {hh[0], hh[1], hh[2], hh[3]};
        ushort4v l4 = {hl[0], hl[1], hl[2], hl[3]};
        *(ushort4v*)(cc.Hhi + cidx) = h4;
        *(ushort4v*)(cc.Hlo + cidx) = l4;
        if (cc.y) {
            #pragma unroll
            for (int e = 0; e < 4; ++e)
                cc.y[(cidx + e) * cc.fut + cc.t] = hn[e];
        }
    }
}

// x_t from seq [B,F,HIST] -> split bf16
__global__ void pack_split(const float* __restrict__ seq,
                           ushort* __restrict__ Xhi, ushort* __restrict__ Xlo, int t)
{
    int idx = blockIdx.x * blockDim.x + threadIdx.x;
    float v = seq[(size_t)idx * HISTLEN + t];
    Xhi[idx] = bfhi(v);
    Xlo[idx] = bflo(v);
}

// fp32 vector -> split bf16 (decoder t=HIST input = c[2])
__global__ void split_vec(const float* __restrict__ src,
                          ushort* __restrict__ hi, ushort* __restrict__ lo)
{
    int idx = blockIdx.x * blockDim.x + threadIdx.x;
    float v = src[idx];
    hi[idx] = bfhi(v);
    lo[idx] = bflo(v);
}

extern "C" void kernel_launch(void* const* d_in, const int* in_sizes, int n_in,
                              void* d_out, int out_size, void* d_ws, size_t ws_size,
                              hipStream_t stream)
{
    const float* seq = (const float*)d_in[0];
    const float* Wih = (const float*)d_in[1];
    const float* Whh = (const float*)d_in[2];
    const float* bih = (const float*)d_in[3];
    const float* bhh = (const float*)d_in[4];
    float* out = (float*)d_out;

    const int fut = out_size / (BDIM * FDIM);   // 30
    const size_t Wsz = (size_t)NG * KD;

    // ws layout (zeroed prefix first):
    //   c[3][BF] f32 | Hs[3][parity2][hi/lo2][BF] u16 | cnt[3*128] u32 || X hi/lo | gp
    float*    c   = (float*)d_ws;
    ushort*   Hs  = (ushort*)(c + LAYERS * BF);
    unsigned* cnt = (unsigned*)(Hs + 12 * BF);
    ushort*   Xhi = (ushort*)(cnt + 3 * 128);
    ushort*   Xlo = Xhi + BF;
    float*    gp  = (float*)(Xlo + BF);

    const size_t zerobytes = LAYERS * BF * sizeof(float) + 12 * BF * sizeof(ushort)
                           + 3 * 128 * sizeof(unsigned);
    hipMemsetAsync(d_ws, 0, zerobytes, stream);

    // capacity-driven encoder batch width
    const size_t fixedbytes = zerobytes + 2 * BF * sizeof(ushort);
    const size_t gpb = 4 * MNc * sizeof(float);            // 32 MB per cell slot
    int Cmax = 1;
    if (ws_size > fixedbytes) {
        size_t avail = (ws_size - fixedbytes) / gpb;
        Cmax = (int)(avail < 1 ? 1 : (avail > 3 ? 3 : avail));
    }

    auto Hh = [&](int l, int par) { return Hs + (((size_t)l * 2 + par) * 2 + 0) * BF; };
    auto Hl = [&](int l, int par) { return Hs + (((size_t)l * 2 + par) * 2 + 1) * BF; };

    const int cgrid = (int)(BF / 256);

    struct CellId { int l, t; };
    auto fill_cell = [&](Args& ar, int i, int l, int t) {
        const ushort *axh, *axl;
        if (l == 0) {
            if (t <= HISTLEN) { axh = Xhi; axl = Xlo; }                 // hist x, or split(c2) at t=HIST
            else { axh = Hh(2, (t - 1) & 1); axl = Hl(2, (t - 1) & 1); }
        } else { axh = Hh(l - 1, t & 1); axl = Hl(l - 1, t & 1); }
        const ushort* ahh = Hh(l, (t - 1) & 1);
        const ushort* ahl = Hl(l, (t - 1) & 1);
        ar.sl[4 * i + 0] = { axh, axl, Wih + (size_t)l * Wsz };
        ar.sl[4 * i + 1] = { axh, axl, Wih + (size_t)l * Wsz };
        ar.sl[4 * i + 2] = { ahh, ahl, Whh + (size_t)l * Wsz };
        ar.sl[4 * i + 3] = { ahh, ahl, Whh + (size_t)l * Wsz };
        CellCtl& cl = ar.cell[i];
        cl.gp  = gp + (size_t)i * 4 * MNc;
        cl.cnt = cnt + i * 128;
        cl.bi = bih + l * NG; cl.bh = bhh + l * NG;
        cl.c = c + (size_t)l * BF;
        cl.Hhi = Hh(l, t & 1); cl.Hlo = Hl(l, t & 1);
        cl.y = (l == LAYERS - 1 && t >= HISTLEN) ? out : nullptr;
        cl.t = t - HISTLEN; cl.fut = fut;
    };

    // ---- encoder: wavefronts w = t + l ----
    for (int w = 0; w < HISTLEN + LAYERS - 1; ++w) {
        if (w < HISTLEN)
            pack_split<<<cgrid, 256, 0, stream>>>(seq, Xhi, Xlo, w);
        CellId list[3]; int n = 0;
        for (int l = 0; l < LAYERS; ++l) {
            int t = w - l;
            if (t >= 0 && t < HISTLEN) list[n++] = { l, t };
        }
        for (int off = 0; off < n; off += Cmax) {
            int C = n - off < Cmax ? n - off : Cmax;
            Args ar;
            for (int i = 0; i < C; ++i) fill_cell(ar, i, list[off + i].l, list[off + i].t);
            dim3 g(FDIM / 32, BDIM / 128, 4 * C);
            gemm_fused<<<g, 256, 0, stream>>>(ar);
        }
    }

    // ---- decoder: strictly sequential cells ----
    split_vec<<<cgrid, 256, 0, stream>>>(c + 2 * BF, Xhi, Xlo);
    for (int t = HISTLEN; t < HISTLEN + fut; ++t) {
        for (int l = 0; l < LAYERS; ++l) {
            Args ar;
            fill_cell(ar, 0, l, t);
            dim3 g(FDIM / 32, BDIM / 128, 4);
            gemm_fused<<<g, 256, 0, stream>>>(ar);
        }
    }
}